// Round 2
// baseline (131.281 us; speedup 1.0000x reference)
//
#include <hip/hip_runtime.h>
#include <type_traits>

typedef short bf16x8 __attribute__((ext_vector_type(8)));
typedef float f32x4 __attribute__((ext_vector_type(4)));

// ---------------- problem constants ----------------
constexpr int Hh = 14, Ww = 14, Cc = 512, Bb = 512, NR = 70, PadR = 80;

// ---------------- constexpr replication of _crop_boxes ----------------
struct Box { int y1, y2, x1, x2; };

constexpr double cfloor(double v) { return (double)(long long)v; }  // v >= 0 only
constexpr double cround(double v) {  // np.round: half-to-even
    double f = cfloor(v);
    double fr = v - f;
    if (fr > 0.5) return f + 1.0;
    if (fr < 0.5) return f;
    return (((long long)f) & 1LL) ? f + 1.0 : f;
}

struct BoxArr { Box b[NR]; };

constexpr BoxArr make_boxes() {
    BoxArr out{};
    double rx_[14] = {}, ry_[14] = {}, wl_[14] = {};
    int nr = 0;
    for (int l = 1; l <= 3; ++l) {
        double wl  = cfloor(2.0 * 14.0 / (double)(l + 1));
        double wl2 = cfloor(wl / 2.0 - 1.0);
        double bb  = (l > 1) ? (14.0 - wl) / (double)(l - 1) : 0.0;
        double cen[3] = {};
        for (int k = 0; k < l; ++k) cen[k] = cfloor(wl2 + (double)k * bb) - wl2;
        for (int i = 0; i < l; ++i)
            for (int j = 0; j < l; ++j) { rx_[nr] = cen[j]; ry_[nr] = cen[i]; wl_[nr] = wl; ++nr; }
    }
    int nb = 0;
    for (int r = 0; r < nr; ++r) {
        for (int p = 1; p <= 2; ++p) {
            double len = wl_[r] / (double)p;
            for (int ix = 0; ix < p; ++ix)
                for (int jy = 0; jy < p; ++jy) {
                    int x1 = (int)cround(rx_[r] + ix * len);
                    int x2 = (int)cround(rx_[r] + ix * len + len);
                    int y1 = (int)cround(ry_[r] + jy * len);
                    int y2 = (int)cround(ry_[r] + jy * len + len);
                    out.b[nb] = Box{y1, y2, x1, x2};
                    ++nb;
                }
        }
    }
    return out;
}
constexpr BoxArr BOXES = make_boxes();

// distinct x-interval dedup
struct Meta { int nxi; int xlo[32]; int xhi[32]; int xid[NR]; };
constexpr Meta make_meta() {
    Meta m{};
    m.nxi = 0;
    for (int r = 0; r < NR; ++r) {
        int lo = BOXES.b[r].x1, hi = BOXES.b[r].x2, id = -1;
        for (int i = 0; i < m.nxi; ++i) if (m.xlo[i] == lo && m.xhi[i] == hi) { id = i; break; }
        if (id < 0) { id = m.nxi; m.xlo[id] = lo; m.xhi[id] = hi; m.nxi++; }
        m.xid[r] = id;
    }
    return m;
}
constexpr Meta MT = make_meta();
constexpr int NXI = MT.nxi;
static_assert(NXI == 14, "expected 14 distinct x-intervals");

__device__ __forceinline__ ushort f2bf(float f) {  // RNE float->bf16 (finite; -inf ok)
    union { float f; unsigned u; } v; v.f = f;
    unsigned r = v.u + 0x7FFFu + ((v.u >> 16) & 1u);
    return (ushort)(r >> 16);
}
__device__ __forceinline__ float bf2f(ushort u) {
    union { unsigned u; float f; } v; v.u = ((unsigned)u) << 16;
    return v.f;
}

// swizzled index into ms[80][128] slice: 16B granule XOR'd by row&7 (matches GEMM read)
__device__ __forceinline__ int midx128(int r, int c) {
    return r * 128 + (((c >> 3) ^ (r & 7)) << 3) + (c & 7);
}

// ---------------- kernel 0: W fp32 -> bf16 ----------------
__global__ __launch_bounds__(256) void k_convw(const float* __restrict__ w,
                                               ushort* __restrict__ o) {
    int i = (blockIdx.x * 256 + threadIdx.x) * 4;
    float4 f = *(const float4*)&w[i];
    ushort4 u;
    u.x = f2bf(f.x); u.y = f2bf(f.y); u.z = f2bf(f.z); u.w = f2bf(f.w);
    *(ushort4*)&o[i] = u;
}

// ---------------- fused, K-pipelined, 2 blocks/CU ----------------
// Per channel-pass cg: pool 128 channels -> ms slice (20 KB) -> MFMA K-slice
// accumulate. LDS ~70 KB -> 2 blocks/CU; independent blocks overlap phases.
__global__ __launch_bounds__(512, 4) void k_fused(const float* __restrict__ x,
                                                  const ushort* __restrict__ wbf,
                                                  const float* __restrict__ bias,
                                                  float* __restrict__ out) {
    __shared__ __align__(16) ushort ms[PadR * 128];          // 20 KB K-slice, swizzled
    __shared__ __align__(16) union UU {
        ushort ims[Hh * NXI * 128];                          // 50 KB (pool passes)
        struct {                                             // epilogue scratch (aliased)
            float rowss[PadR][8];
            float rns[PadR];
            float y_s[Cc];
            float red2[8];
        } e;
    } u;
    __shared__ float ss_s[PadR];
    __shared__ float rnm[PadR];

    const int b = blockIdx.x;
    const int tid = threadIdx.x;
    const int lane = tid & 63;
    const int wv = tid >> 6;                // 0..7
    const int l15 = lane & 15, lhi = lane >> 4;

    // zero pad rows of ms (rows 70..79: 2560 B = 640 uints) and tail of ss_s
    {
        uint* z = (uint*)&ms[70 * 128];
        z[tid] = 0;
        if (tid < 128) z[512 + tid] = 0;
        if (tid >= 70 && tid < PadR) ss_s[tid] = 0.f;
    }

    float ssacc[9];
    #pragma unroll
    for (int i = 0; i < 9; ++i) ssacc[i] = 0.f;

    f32x4 acc[5][4];
    #pragma unroll
    for (int mi = 0; mi < 5; ++mi)
        #pragma unroll
        for (int ni = 0; ni < 4; ++ni) acc[mi][ni] = (f32x4){0.f, 0.f, 0.f, 0.f};

    // ---- phase A: x-fold 128 channels of pass cg into ims ----
    auto phaseA = [&](int cg) {
        #pragma unroll
        for (int rb = 0; rb < 2; ++rb) {
            const int h = wv + rb * 8;
            if (h < Hh) {
                const float2* xq = (const float2*)(x + (size_t)b * Hh * Ww * Cc
                                                   + (size_t)h * Ww * Cc + cg * 128 + lane * 2);
                float2 row[Ww];
                #pragma unroll
                for (int w = 0; w < Ww; ++w) row[w] = xq[w * (Cc / 2)];
                #pragma unroll
                for (int xi = 0; xi < NXI; ++xi) {
                    float2 mm = row[MT.xlo[xi]];
                    #pragma unroll
                    for (int w = MT.xlo[xi] + 1; w < MT.xhi[xi]; ++w) {
                        mm.x = fmaxf(mm.x, row[w].x); mm.y = fmaxf(mm.y, row[w].y);
                    }
                    ushort2 o;
                    o.x = f2bf(mm.x); o.y = f2bf(mm.y);
                    *(ushort2*)&u.ims[(h * NXI + xi) * 128 + lane * 2] = o;
                }
            }
        }
    };

    phaseA(0);
    __syncthreads();

    for (int cg = 0; cg < 4; ++cg) {
        // ---- phase B: y-fold, 8 wave-groups x 9 boxes (guarded), write ms slice ----
        auto fold = [&](auto GC) {
            constexpr int G = GC.value;
            #pragma unroll
            for (int i = 0; i < 9; ++i) {
                constexpr int dummy = 0; (void)dummy;
                const int rr = G * 9 + i;                    // unroll-time constant
                if (rr < NR) {
                    float m0 = -INFINITY, m1 = -INFINITY;
                    #pragma unroll
                    for (int h = BOXES.b[rr < NR ? rr : 0].y1;
                         h < BOXES.b[rr < NR ? rr : 0].y2; ++h) {
                        ushort2 t2 = *(const ushort2*)
                            &u.ims[(h * NXI + MT.xid[rr < NR ? rr : 0]) * 128 + 2 * lane];
                        m0 = fmaxf(m0, bf2f(t2.x)); m1 = fmaxf(m1, bf2f(t2.y));
                    }
                    ushort2 o; o.x = f2bf(m0); o.y = f2bf(m1);
                    *(ushort2*)&ms[midx128(rr, 2 * lane)] = o;
                    ssacc[i] += m0 * m0 + m1 * m1;
                }
            }
        };
        if      (wv == 0) fold(std::integral_constant<int, 0>{});
        else if (wv == 1) fold(std::integral_constant<int, 1>{});
        else if (wv == 2) fold(std::integral_constant<int, 2>{});
        else if (wv == 3) fold(std::integral_constant<int, 3>{});
        else if (wv == 4) fold(std::integral_constant<int, 4>{});
        else if (wv == 5) fold(std::integral_constant<int, 5>{});
        else if (wv == 6) fold(std::integral_constant<int, 6>{});
        else              fold(std::integral_constant<int, 7>{});
        __syncthreads();

        // ---- GEMM on this K-slice: acc += ms(80x128) * W^T-slice ----
        #pragma unroll
        for (int ks4 = 0; ks4 < 4; ++ks4) {
            bf16x8 bf[4];
            #pragma unroll
            for (int ni = 0; ni < 4; ++ni)
                bf[ni] = *(const bf16x8*)(wbf + (size_t)(wv * 64 + ni * 16 + l15) * Cc
                                          + cg * 128 + ks4 * 32 + lhi * 8);
            #pragma unroll
            for (int mi = 0; mi < 5; ++mi) {
                const int row = mi * 16 + l15;
                const int slot = (ks4 * 4 + lhi) ^ (row & 7);
                bf16x8 af = *(const bf16x8*)&ms[row * 128 + slot * 8];
                #pragma unroll
                for (int ni = 0; ni < 4; ++ni)
                    acc[mi][ni] = __builtin_amdgcn_mfma_f32_16x16x32_bf16(
                        af, bf[ni], acc[mi][ni], 0, 0, 0);
            }
        }

        // ---- prefetch-pool next pass (after GEMM; ims reads all done pre-barrier) ----
        if (cg < 3) phaseA(cg + 1);
        __syncthreads();     // ms reads (GEMM) & ims writes (A') done before next B
    }

    // ---- publish SS (one butterfly per box), compute rnm ----
    #pragma unroll
    for (int i = 0; i < 9; ++i) {
        float s = ssacc[i];
        s += __shfl_xor(s, 1);  s += __shfl_xor(s, 2);  s += __shfl_xor(s, 4);
        s += __shfl_xor(s, 8);  s += __shfl_xor(s, 16); s += __shfl_xor(s, 32);
        if (lane == 0 && wv * 9 + i < NR) ss_s[wv * 9 + i] = s;
    }
    __syncthreads();
    if (tid < PadR) rnm[tid] = 1.f / fmaxf(sqrtf(ss_s[tid]), 1e-12f);
    __syncthreads();

    // ---- fused epilogue: deferred A-norm + bias, row-norm, sum, final norm ----
    float bia[4];
    #pragma unroll
    for (int ni = 0; ni < 4; ++ni) bia[ni] = bias[wv * 64 + ni * 16 + l15];
    float rm[5][4];
    #pragma unroll
    for (int mi = 0; mi < 5; ++mi)
        #pragma unroll
        for (int j = 0; j < 4; ++j) rm[mi][j] = rnm[mi * 16 + lhi * 4 + j];
    #pragma unroll
    for (int mi = 0; mi < 5; ++mi)
        #pragma unroll
        for (int ni = 0; ni < 4; ++ni)
            #pragma unroll
            for (int j = 0; j < 4; ++j)
                acc[mi][ni][j] = fmaf(acc[mi][ni][j], rm[mi][j], bia[ni]);

    #pragma unroll
    for (int mi = 0; mi < 5; ++mi)
        #pragma unroll
        for (int j = 0; j < 4; ++j) {
            float s = 0.f;
            #pragma unroll
            for (int ni = 0; ni < 4; ++ni) s += acc[mi][ni][j] * acc[mi][ni][j];
            s += __shfl_xor(s, 1); s += __shfl_xor(s, 2);
            s += __shfl_xor(s, 4); s += __shfl_xor(s, 8);
            if (l15 == 0) u.e.rowss[mi * 16 + lhi * 4 + j][wv] = s;
        }
    __syncthreads();
    if (tid < PadR) {
        float s = 0.f;
        #pragma unroll
        for (int w8 = 0; w8 < 8; ++w8) s += u.e.rowss[tid][w8];
        u.e.rns[tid] = 1.f / fmaxf(sqrtf(s), 1e-12f);
    }
    __syncthreads();

    float ys[4] = {0.f, 0.f, 0.f, 0.f};
    #pragma unroll
    for (int mi = 0; mi < 5; ++mi)
        #pragma unroll
        for (int j = 0; j < 4; ++j) {
            int row = mi * 16 + lhi * 4 + j;
            float w = (row < NR) ? u.e.rns[row] : 0.f;   // skip pad rows
            #pragma unroll
            for (int ni = 0; ni < 4; ++ni) ys[ni] = fmaf(acc[mi][ni][j], w, ys[ni]);
        }
    #pragma unroll
    for (int ni = 0; ni < 4; ++ni) {
        ys[ni] += __shfl_xor(ys[ni], 16);
        ys[ni] += __shfl_xor(ys[ni], 32);
    }
    if (lane < 16)
        #pragma unroll
        for (int ni = 0; ni < 4; ++ni) u.e.y_s[wv * 64 + ni * 16 + lane] = ys[ni];
    __syncthreads();

    float yv = u.e.y_s[tid];
    float s2 = yv * yv;
    s2 += __shfl_xor(s2, 1);  s2 += __shfl_xor(s2, 2);  s2 += __shfl_xor(s2, 4);
    s2 += __shfl_xor(s2, 8);  s2 += __shfl_xor(s2, 16); s2 += __shfl_xor(s2, 32);
    if (lane == 0) u.e.red2[wv] = s2;
    __syncthreads();
    float tot = 0.f;
    #pragma unroll
    for (int w8 = 0; w8 < 8; ++w8) tot += u.e.red2[w8];
    out[(size_t)b * Cc + tid] = yv / fmaxf(sqrtf(tot), 1e-12f);
}

// ---------------- launch ----------------
extern "C" void kernel_launch(void* const* d_in, const int* in_sizes, int n_in,
                              void* d_out, int out_size, void* d_ws, size_t ws_size,
                              hipStream_t stream) {
    const float* x  = (const float*)d_in[0];
    const float* pw = (const float*)d_in[1];
    const float* pb = (const float*)d_in[2];
    float* out = (float*)d_out;

    ushort* wbf = (ushort*)d_ws;                          // 512x512 bf16 = 0.5 MB

    k_convw<<<dim3(256), dim3(256), 0, stream>>>(pw, wbf);
    k_fused<<<dim3(Bb), dim3(512), 0, stream>>>(x, wbf, pb, out);
}

// Round 3
// 92.481 us; speedup vs baseline: 1.4195x; 1.4195x over previous
//
#include <hip/hip_runtime.h>
#include <type_traits>

typedef short bf16x8 __attribute__((ext_vector_type(8)));
typedef float f32x4 __attribute__((ext_vector_type(4)));

// ---------------- problem constants ----------------
constexpr int Hh = 14, Ww = 14, Cc = 512, Bb = 512, NR = 70, PadR = 80;

// ---------------- constexpr replication of _crop_boxes ----------------
struct Box { int y1, y2, x1, x2; };

constexpr double cfloor(double v) { return (double)(long long)v; }  // v >= 0 only
constexpr double cround(double v) {  // np.round: half-to-even
    double f = cfloor(v);
    double fr = v - f;
    if (fr > 0.5) return f + 1.0;
    if (fr < 0.5) return f;
    return (((long long)f) & 1LL) ? f + 1.0 : f;
}

struct BoxArr { Box b[NR]; };

constexpr BoxArr make_boxes() {
    BoxArr out{};
    double rx_[14] = {}, ry_[14] = {}, wl_[14] = {};
    int nr = 0;
    for (int l = 1; l <= 3; ++l) {
        double wl  = cfloor(2.0 * 14.0 / (double)(l + 1));
        double wl2 = cfloor(wl / 2.0 - 1.0);
        double bb  = (l > 1) ? (14.0 - wl) / (double)(l - 1) : 0.0;
        double cen[3] = {};
        for (int k = 0; k < l; ++k) cen[k] = cfloor(wl2 + (double)k * bb) - wl2;
        for (int i = 0; i < l; ++i)
            for (int j = 0; j < l; ++j) { rx_[nr] = cen[j]; ry_[nr] = cen[i]; wl_[nr] = wl; ++nr; }
    }
    int nb = 0;
    for (int r = 0; r < nr; ++r) {
        for (int p = 1; p <= 2; ++p) {
            double len = wl_[r] / (double)p;
            for (int ix = 0; ix < p; ++ix)
                for (int jy = 0; jy < p; ++jy) {
                    int x1 = (int)cround(rx_[r] + ix * len);
                    int x2 = (int)cround(rx_[r] + ix * len + len);
                    int y1 = (int)cround(ry_[r] + jy * len);
                    int y2 = (int)cround(ry_[r] + jy * len + len);
                    out.b[nb] = Box{y1, y2, x1, x2};
                    ++nb;
                }
        }
    }
    return out;
}
constexpr BoxArr BOXES = make_boxes();

// distinct x-interval dedup
struct Meta { int nxi; int xlo[32]; int xhi[32]; int xid[NR]; };
constexpr Meta make_meta() {
    Meta m{};
    m.nxi = 0;
    for (int r = 0; r < NR; ++r) {
        int lo = BOXES.b[r].x1, hi = BOXES.b[r].x2, id = -1;
        for (int i = 0; i < m.nxi; ++i) if (m.xlo[i] == lo && m.xhi[i] == hi) { id = i; break; }
        if (id < 0) { id = m.nxi; m.xlo[id] = lo; m.xhi[id] = hi; m.nxi++; }
        m.xid[r] = id;
    }
    return m;
}
constexpr Meta MT = make_meta();
constexpr int NXI = MT.nxi;
static_assert(NXI == 14, "expected 14 distinct x-intervals");

__device__ __forceinline__ ushort f2bf(float f) {  // RNE float->bf16 (finite; -inf ok)
    union { float f; unsigned u; } v; v.f = f;
    unsigned r = v.u + 0x7FFFu + ((v.u >> 16) & 1u);
    return (ushort)(r >> 16);
}
__device__ __forceinline__ float bf2f(ushort u) {
    union { unsigned u; float f; } v; v.u = ((unsigned)u) << 16;
    return v.f;
}

// swizzled index into m[80][512]: 16B slots XOR'd by row&7 (matches GEMM read)
__device__ __forceinline__ int midx(int r, int c) {
    return r * Cc + (((c >> 3) ^ (r & 7)) << 3) + (c & 7);
}

// ---------------- kernel 0: W fp32 -> bf16 ----------------
__global__ __launch_bounds__(256) void k_convw(const float* __restrict__ w,
                                               ushort* __restrict__ o) {
    int i = (blockIdx.x * 256 + threadIdx.x) * 4;
    float4 f = *(const float4*)&w[i];
    ushort4 u;
    u.x = f2bf(f.x); u.y = f2bf(f.y); u.z = f2bf(f.z); u.w = f2bf(f.w);
    *(ushort4*)&o[i] = u;
}

// ---------------- kernel 1: pooling, one (b, cg) slice per block ----------------
// grid 2048 = 512 b x 4 cg. LDS 50 KB (3 blocks/CU), no accumulators -> low VGPR.
// Writes m (bf16, pre-XOR-swizzled layout) + per-cg row sum-of-squares partials.
__global__ __launch_bounds__(512, 4) void k_pool(const float* __restrict__ x,
                                                 ushort* __restrict__ mg,
                                                 float* __restrict__ ssp) {
    __shared__ __align__(16) ushort ims[Hh * NXI * 128];     // 50 KB
    const int bid = blockIdx.x;
    const int b = bid >> 2, cg = bid & 3;
    const int tid = threadIdx.x;
    const int lane = tid & 63;
    const int wv = tid >> 6;                 // 0..7

    // ---- phase A: x-fold (rows h = wv, wv+8), float2 = 2 channels/lane ----
    #pragma unroll
    for (int rb = 0; rb < 2; ++rb) {
        const int h = wv + rb * 8;
        if (h < Hh) {
            const float2* xq = (const float2*)(x + (size_t)b * Hh * Ww * Cc
                                               + (size_t)h * Ww * Cc + cg * 128 + lane * 2);
            float2 row[Ww];
            #pragma unroll
            for (int w = 0; w < Ww; ++w) row[w] = xq[w * (Cc / 2)];
            #pragma unroll
            for (int xi = 0; xi < NXI; ++xi) {
                float2 mm = row[MT.xlo[xi]];
                #pragma unroll
                for (int w = MT.xlo[xi] + 1; w < MT.xhi[xi]; ++w) {
                    mm.x = fmaxf(mm.x, row[w].x); mm.y = fmaxf(mm.y, row[w].y);
                }
                ushort2 o;
                o.x = f2bf(mm.x); o.y = f2bf(mm.y);
                *(ushort2*)&ims[(h * NXI + xi) * 128 + lane * 2] = o;
            }
        }
    }
    __syncthreads();

    // ---- phase B: y-fold, 8 waves x 9 boxes (guarded), write m + SS partial ----
    float ssacc[9];
    #pragma unroll
    for (int i = 0; i < 9; ++i) ssacc[i] = 0.f;

    auto fold = [&](auto GC) {
        constexpr int G = GC.value;
        #pragma unroll
        for (int i = 0; i < 9; ++i) {
            const int rr = G * 9 + i;                        // unroll-time constant
            if (rr < NR) {
                float m0 = -INFINITY, m1 = -INFINITY;
                #pragma unroll
                for (int h = BOXES.b[rr < NR ? rr : 0].y1;
                     h < BOXES.b[rr < NR ? rr : 0].y2; ++h) {
                    ushort2 t2 = *(const ushort2*)
                        &ims[(h * NXI + MT.xid[rr < NR ? rr : 0]) * 128 + 2 * lane];
                    m0 = fmaxf(m0, bf2f(t2.x)); m1 = fmaxf(m1, bf2f(t2.y));
                }
                ushort2 o; o.x = f2bf(m0); o.y = f2bf(m1);
                *(ushort2*)&mg[(size_t)b * (PadR * Cc) + midx(rr, cg * 128 + 2 * lane)] = o;
                ssacc[i] += m0 * m0 + m1 * m1;
            }
        }
    };
    if      (wv == 0) fold(std::integral_constant<int, 0>{});
    else if (wv == 1) fold(std::integral_constant<int, 1>{});
    else if (wv == 2) fold(std::integral_constant<int, 2>{});
    else if (wv == 3) fold(std::integral_constant<int, 3>{});
    else if (wv == 4) fold(std::integral_constant<int, 4>{});
    else if (wv == 5) fold(std::integral_constant<int, 5>{});
    else if (wv == 6) fold(std::integral_constant<int, 6>{});
    else              fold(std::integral_constant<int, 7>{});

    // butterfly per box, lane 0 writes SS partial for this cg
    #pragma unroll
    for (int i = 0; i < 9; ++i) {
        float s = ssacc[i];
        s += __shfl_xor(s, 1);  s += __shfl_xor(s, 2);  s += __shfl_xor(s, 4);
        s += __shfl_xor(s, 8);  s += __shfl_xor(s, 16); s += __shfl_xor(s, 32);
        if (lane == 0 && wv * 9 + i < NR)
            ssp[(size_t)b * 320 + cg * 80 + wv * 9 + i] = s;
    }
}

// ---------------- kernel 2: GEMM + fused norm epilogue, one b per block ----------
__global__ __launch_bounds__(512) void k_gemm(const ushort* __restrict__ mg,
                                              const float* __restrict__ ssp,
                                              const ushort* __restrict__ wbf,
                                              const float* __restrict__ bias,
                                              float* __restrict__ out) {
    __shared__ __align__(16) ushort m_s[PadR * Cc];          // 80 KB (swizzled layout)
    __shared__ float rnm[PadR];
    __shared__ float rowss[PadR][8];
    __shared__ float rns[PadR];
    __shared__ float y_s[Cc];
    __shared__ float red2[8];

    const int b = blockIdx.x;
    const int tid = threadIdx.x;
    const int lane = tid & 63;
    const int wv = tid >> 6;                // 0..7
    const int l15 = lane & 15, lhi = lane >> 4;

    // ---- stage m rows 0..69 (4480 x 16B), zero pad rows 70..79 ----
    {
        const bf16x8* src = (const bf16x8*)(mg + (size_t)b * (PadR * Cc));
        bf16x8* dst = (bf16x8*)m_s;
        #pragma unroll
        for (int i = 0; i < 8; ++i) dst[tid + i * 512] = src[tid + i * 512];
        if (tid < 384) dst[tid + 4096] = src[tid + 4096];
        uint* z = (uint*)&m_s[70 * Cc];
        #pragma unroll
        for (int i = 0; i < 5; ++i) z[tid + i * 512] = 0;
    }
    if (tid < PadR) {
        if (tid < NR) {
            float s = 0.f;
            #pragma unroll
            for (int c = 0; c < 4; ++c) s += ssp[(size_t)b * 320 + c * 80 + tid];
            rnm[tid] = 1.f / fmaxf(sqrtf(s), 1e-12f);
        } else rnm[tid] = 0.f;               // pad rows: zero scale (keeps acc finite)
    }
    __syncthreads();

    // ---- GEMM: t[80][512] = m * W^T, A resident in m_s, no barriers ----
    f32x4 acc[5][4];
    #pragma unroll
    for (int mi = 0; mi < 5; ++mi)
        #pragma unroll
        for (int ni = 0; ni < 4; ++ni) acc[mi][ni] = (f32x4){0.f, 0.f, 0.f, 0.f};

    auto loadB = [&](bf16x8 (&bf)[4][2], int k0) {
        #pragma unroll
        for (int ni = 0; ni < 4; ++ni)
            #pragma unroll
            for (int kh = 0; kh < 2; ++kh)
                bf[ni][kh] = *(const bf16x8*)(wbf + (size_t)(wv * 64 + ni * 16 + l15) * Cc
                                              + k0 + kh * 32 + lhi * 8);
    };

    bf16x8 bfc[4][2], bfn[4][2];
    loadB(bfc, 0);
    #pragma unroll
    for (int ks = 0; ks < 8; ++ks) {
        if (ks < 7) loadB(bfn, (ks + 1) * 64);
        #pragma unroll
        for (int kh = 0; kh < 2; ++kh) {
            bf16x8 af[5];
            #pragma unroll
            for (int mi = 0; mi < 5; ++mi) {
                int row = mi * 16 + l15;
                int slot = (ks * 8 + kh * 4 + lhi) ^ (row & 7);
                af[mi] = *(const bf16x8*)&m_s[row * Cc + slot * 8];
            }
            #pragma unroll
            for (int mi = 0; mi < 5; ++mi)
                #pragma unroll
                for (int ni = 0; ni < 4; ++ni)
                    acc[mi][ni] = __builtin_amdgcn_mfma_f32_16x16x32_bf16(
                        af[mi], bfc[ni][kh], acc[mi][ni], 0, 0, 0);
        }
        #pragma unroll
        for (int ni = 0; ni < 4; ++ni)
            #pragma unroll
            for (int kh = 0; kh < 2; ++kh) bfc[ni][kh] = bfn[ni][kh];
    }

    // ---- fused epilogue: deferred A-norm + bias, row-norm, sum, final norm ----
    float bia[4];
    #pragma unroll
    for (int ni = 0; ni < 4; ++ni) bia[ni] = bias[wv * 64 + ni * 16 + l15];
    float rm[5][4];
    #pragma unroll
    for (int mi = 0; mi < 5; ++mi)
        #pragma unroll
        for (int j = 0; j < 4; ++j) rm[mi][j] = rnm[mi * 16 + lhi * 4 + j];
    #pragma unroll
    for (int mi = 0; mi < 5; ++mi)
        #pragma unroll
        for (int ni = 0; ni < 4; ++ni)
            #pragma unroll
            for (int j = 0; j < 4; ++j)
                acc[mi][ni][j] = fmaf(acc[mi][ni][j], rm[mi][j], bia[ni]);

    #pragma unroll
    for (int mi = 0; mi < 5; ++mi)
        #pragma unroll
        for (int j = 0; j < 4; ++j) {
            float s = 0.f;
            #pragma unroll
            for (int ni = 0; ni < 4; ++ni) s += acc[mi][ni][j] * acc[mi][ni][j];
            s += __shfl_xor(s, 1); s += __shfl_xor(s, 2);
            s += __shfl_xor(s, 4); s += __shfl_xor(s, 8);
            if (l15 == 0) rowss[mi * 16 + lhi * 4 + j][wv] = s;
        }
    __syncthreads();
    if (tid < PadR) {
        float s = 0.f;
        #pragma unroll
        for (int w8 = 0; w8 < 8; ++w8) s += rowss[tid][w8];
        rns[tid] = 1.f / fmaxf(sqrtf(s), 1e-12f);
    }
    __syncthreads();

    float ys[4] = {0.f, 0.f, 0.f, 0.f};
    #pragma unroll
    for (int mi = 0; mi < 5; ++mi)
        #pragma unroll
        for (int j = 0; j < 4; ++j) {
            int row = mi * 16 + lhi * 4 + j;
            float w = (row < NR) ? rns[row] : 0.f;   // skip pad rows
            #pragma unroll
            for (int ni = 0; ni < 4; ++ni) ys[ni] = fmaf(acc[mi][ni][j], w, ys[ni]);
        }
    #pragma unroll
    for (int ni = 0; ni < 4; ++ni) {
        ys[ni] += __shfl_xor(ys[ni], 16);
        ys[ni] += __shfl_xor(ys[ni], 32);
    }
    if (lane < 16)
        #pragma unroll
        for (int ni = 0; ni < 4; ++ni) y_s[wv * 64 + ni * 16 + lane] = ys[ni];
    __syncthreads();

    float yv = y_s[tid];
    float s2 = yv * yv;
    s2 += __shfl_xor(s2, 1);  s2 += __shfl_xor(s2, 2);  s2 += __shfl_xor(s2, 4);
    s2 += __shfl_xor(s2, 8);  s2 += __shfl_xor(s2, 16); s2 += __shfl_xor(s2, 32);
    if (lane == 0) red2[wv] = s2;
    __syncthreads();
    float tot = 0.f;
    #pragma unroll
    for (int w8 = 0; w8 < 8; ++w8) tot += red2[w8];
    out[(size_t)b * Cc + tid] = yv / fmaxf(sqrtf(tot), 1e-12f);
}

// ---------------- fallback: round-0 fused kernel (known-good, 91 us) ------------
__global__ __launch_bounds__(512) void k_fused_fb(const float* __restrict__ x,
                                                  const ushort* __restrict__ wbf,
                                                  const float* __restrict__ bias,
                                                  float* __restrict__ out) {
    __shared__ __align__(16) ushort m_s[PadR * Cc];
    __shared__ __align__(16) union UU {
        ushort ims[Hh * NXI * 128];
        struct {
            float rowss[PadR][8];
            float rns[PadR];
            float y_s[Cc];
            float red2[8];
        } e;
    } u;
    __shared__ float ss_s[PadR];
    __shared__ float rnm[PadR];

    const int b = blockIdx.x;
    const int tid = threadIdx.x;
    const int lane = tid & 63;
    const int wv = tid >> 6;
    const int l15 = lane & 15, lhi = lane >> 4;

    {
        uint* z = (uint*)&m_s[70 * Cc];
        #pragma unroll
        for (int i = 0; i < 5; ++i) z[tid + i * 512] = 0;
        if (tid >= 70 && tid < PadR) ss_s[tid] = 0.f;
    }

    float ssacc[9];
    #pragma unroll
    for (int i = 0; i < 9; ++i) ssacc[i] = 0.f;

    const int q  = tid & 31;
    const int hA = tid >> 5;
    const int c2 = tid & 63;
    const int grp = tid >> 6;

    for (int cg = 0; cg < 4; ++cg) {
        if (hA < Hh) {
            const float4* xq = (const float4*)(x + (size_t)b * Hh * Ww * Cc
                                               + (size_t)hA * Ww * Cc + cg * 128 + q * 4);
            float4 row[Ww];
            #pragma unroll
            for (int w = 0; w < Ww; ++w) row[w] = xq[w * (Cc / 4)];
            #pragma unroll
            for (int xi = 0; xi < NXI; ++xi) {
                float4 mm = row[MT.xlo[xi]];
                #pragma unroll
                for (int w = MT.xlo[xi] + 1; w < MT.xhi[xi]; ++w) {
                    mm.x = fmaxf(mm.x, row[w].x); mm.y = fmaxf(mm.y, row[w].y);
                    mm.z = fmaxf(mm.z, row[w].z); mm.w = fmaxf(mm.w, row[w].w);
                }
                ushort4 o;
                o.x = f2bf(mm.x); o.y = f2bf(mm.y); o.z = f2bf(mm.z); o.w = f2bf(mm.w);
                *(ushort4*)&u.ims[(hA * NXI + xi) * 128 + q * 4] = o;
            }
        }
        __syncthreads();

        auto fold = [&](auto GC) {
            constexpr int G = GC.value;
            #pragma unroll
            for (int i = 0; i < 9; ++i) {
                const int rr = G * 9 + i;
                if (rr < NR) {
                    float m0 = -INFINITY, m1 = -INFINITY;
                    #pragma unroll
                    for (int h = BOXES.b[rr < NR ? rr : 0].y1;
                         h < BOXES.b[rr < NR ? rr : 0].y2; ++h) {
                        ushort2 t2 = *(const ushort2*)
                            &u.ims[(h * NXI + MT.xid[rr < NR ? rr : 0]) * 128 + 2 * c2];
                        m0 = fmaxf(m0, bf2f(t2.x)); m1 = fmaxf(m1, bf2f(t2.y));
                    }
                    ushort2 o; o.x = f2bf(m0); o.y = f2bf(m1);
                    *(ushort2*)&m_s[midx(rr, cg * 128 + 2 * c2)] = o;
                    ssacc[i] += m0 * m0 + m1 * m1;
                }
            }
        };
        if      (grp == 0) fold(std::integral_constant<int, 0>{});
        else if (grp == 1) fold(std::integral_constant<int, 1>{});
        else if (grp == 2) fold(std::integral_constant<int, 2>{});
        else if (grp == 3) fold(std::integral_constant<int, 3>{});
        else if (grp == 4) fold(std::integral_constant<int, 4>{});
        else if (grp == 5) fold(std::integral_constant<int, 5>{});
        else if (grp == 6) fold(std::integral_constant<int, 6>{});
        else               fold(std::integral_constant<int, 7>{});
        __syncthreads();
    }

    #pragma unroll
    for (int i = 0; i < 9; ++i) {
        float s = ssacc[i];
        s += __shfl_xor(s, 1);  s += __shfl_xor(s, 2);  s += __shfl_xor(s, 4);
        s += __shfl_xor(s, 8);  s += __shfl_xor(s, 16); s += __shfl_xor(s, 32);
        if (lane == 0 && grp * 9 + i < NR) ss_s[grp * 9 + i] = s;
    }
    __syncthreads();
    if (tid < PadR) rnm[tid] = 1.f / fmaxf(sqrtf(ss_s[tid]), 1e-12f);
    __syncthreads();

    f32x4 acc[5][4];
    #pragma unroll
    for (int mi = 0; mi < 5; ++mi)
        #pragma unroll
        for (int ni = 0; ni < 4; ++ni) acc[mi][ni] = (f32x4){0.f, 0.f, 0.f, 0.f};

    auto loadB = [&](bf16x8 (&bf)[4][2], int k0) {
        #pragma unroll
        for (int ni = 0; ni < 4; ++ni)
            #pragma unroll
            for (int kh = 0; kh < 2; ++kh)
                bf[ni][kh] = *(const bf16x8*)(wbf + (size_t)(wv * 64 + ni * 16 + l15) * Cc
                                              + k0 + kh * 32 + lhi * 8);
    };

    bf16x8 bfc[4][2], bfn[4][2];
    loadB(bfc, 0);
    #pragma unroll
    for (int ks = 0; ks < 8; ++ks) {
        if (ks < 7) loadB(bfn, (ks + 1) * 64);
        #pragma unroll
        for (int kh = 0; kh < 2; ++kh) {
            bf16x8 af[5];
            #pragma unroll
            for (int mi = 0; mi < 5; ++mi) {
                int row = mi * 16 + l15;
                int slot = (ks * 8 + kh * 4 + lhi) ^ (row & 7);
                af[mi] = *(const bf16x8*)&m_s[row * Cc + slot * 8];
            }
            #pragma unroll
            for (int mi = 0; mi < 5; ++mi)
                #pragma unroll
                for (int ni = 0; ni < 4; ++ni)
                    acc[mi][ni] = __builtin_amdgcn_mfma_f32_16x16x32_bf16(
                        af[mi], bfc[ni][kh], acc[mi][ni], 0, 0, 0);
        }
        #pragma unroll
        for (int ni = 0; ni < 4; ++ni)
            #pragma unroll
            for (int kh = 0; kh < 2; ++kh) bfc[ni][kh] = bfn[ni][kh];
    }
    __syncthreads();

    float bia[4];
    #pragma unroll
    for (int ni = 0; ni < 4; ++ni) bia[ni] = bias[wv * 64 + ni * 16 + l15];
    float rm[5][4];
    #pragma unroll
    for (int mi = 0; mi < 5; ++mi)
        #pragma unroll
        for (int j = 0; j < 4; ++j) rm[mi][j] = rnm[mi * 16 + lhi * 4 + j];
    #pragma unroll
    for (int mi = 0; mi < 5; ++mi)
        #pragma unroll
        for (int ni = 0; ni < 4; ++ni)
            #pragma unroll
            for (int j = 0; j < 4; ++j)
                acc[mi][ni][j] = fmaf(acc[mi][ni][j], rm[mi][j], bia[ni]);

    #pragma unroll
    for (int mi = 0; mi < 5; ++mi)
        #pragma unroll
        for (int j = 0; j < 4; ++j) {
            float s = 0.f;
            #pragma unroll
            for (int ni = 0; ni < 4; ++ni) s += acc[mi][ni][j] * acc[mi][ni][j];
            s += __shfl_xor(s, 1); s += __shfl_xor(s, 2);
            s += __shfl_xor(s, 4); s += __shfl_xor(s, 8);
            if (l15 == 0) u.e.rowss[mi * 16 + lhi * 4 + j][wv] = s;
        }
    __syncthreads();
    if (tid < PadR) {
        float s = 0.f;
        #pragma unroll
        for (int w8 = 0; w8 < 8; ++w8) s += u.e.rowss[tid][w8];
        u.e.rns[tid] = 1.f / fmaxf(sqrtf(s), 1e-12f);
    }
    __syncthreads();

    float ys[4] = {0.f, 0.f, 0.f, 0.f};
    #pragma unroll
    for (int mi = 0; mi < 5; ++mi)
        #pragma unroll
        for (int j = 0; j < 4; ++j) {
            int row = mi * 16 + lhi * 4 + j;
            float w = (row < NR) ? u.e.rns[row] : 0.f;
            #pragma unroll
            for (int ni = 0; ni < 4; ++ni) ys[ni] = fmaf(acc[mi][ni][j], w, ys[ni]);
        }
    #pragma unroll
    for (int ni = 0; ni < 4; ++ni) {
        ys[ni] += __shfl_xor(ys[ni], 16);
        ys[ni] += __shfl_xor(ys[ni], 32);
    }
    if (lane < 16)
        #pragma unroll
        for (int ni = 0; ni < 4; ++ni) u.e.y_s[wv * 64 + ni * 16 + lane] = ys[ni];
    __syncthreads();

    float yv = u.e.y_s[tid];
    float s2 = yv * yv;
    s2 += __shfl_xor(s2, 1);  s2 += __shfl_xor(s2, 2);  s2 += __shfl_xor(s2, 4);
    s2 += __shfl_xor(s2, 8);  s2 += __shfl_xor(s2, 16); s2 += __shfl_xor(s2, 32);
    if (lane == 0) u.e.red2[wv] = s2;
    __syncthreads();
    float tot = 0.f;
    #pragma unroll
    for (int w8 = 0; w8 < 8; ++w8) tot += u.e.red2[w8];
    out[(size_t)b * Cc + tid] = yv / fmaxf(sqrtf(tot), 1e-12f);
}

// ---------------- launch ----------------
extern "C" void kernel_launch(void* const* d_in, const int* in_sizes, int n_in,
                              void* d_out, int out_size, void* d_ws, size_t ws_size,
                              hipStream_t stream) {
    const float* x  = (const float*)d_in[0];
    const float* pw = (const float*)d_in[1];
    const float* pb = (const float*)d_in[2];
    float* out = (float*)d_out;

    // workspace layout: wbf (0.5 MB) | mg (40 MB) | ssp (0.64 MB)
    constexpr size_t OFF_WBF = 0;
    constexpr size_t OFF_MG  = 524288;
    constexpr size_t OFF_SSP = OFF_MG + (size_t)Bb * PadR * Cc * 2;   // 42467328
    constexpr size_t NEEDED  = OFF_SSP + (size_t)Bb * 4 * PadR * 4;   // 43122688

    ushort* wbf = (ushort*)((char*)d_ws + OFF_WBF);
    k_convw<<<dim3(256), dim3(256), 0, stream>>>(pw, wbf);

    if (ws_size >= NEEDED) {
        ushort* mg = (ushort*)((char*)d_ws + OFF_MG);
        float* ssp = (float*)((char*)d_ws + OFF_SSP);
        k_pool<<<dim3(Bb * 4), dim3(512), 0, stream>>>(x, mg, ssp);
        k_gemm<<<dim3(Bb), dim3(512), 0, stream>>>(mg, ssp, wbf, pb, out);
    } else {
        k_fused_fb<<<dim3(Bb), dim3(512), 0, stream>>>(x, wbf, pb, out);
    }
}

// Round 4
// 91.604 us; speedup vs baseline: 1.4331x; 1.0096x over previous
//
#include <hip/hip_runtime.h>
#include <type_traits>

typedef short bf16x8 __attribute__((ext_vector_type(8)));
typedef float f32x4 __attribute__((ext_vector_type(4)));

// ---------------- problem constants ----------------
constexpr int Hh = 14, Ww = 14, Cc = 512, Bb = 512, NR = 70, PadR = 80;

// ---------------- constexpr replication of _crop_boxes ----------------
struct Box { int y1, y2, x1, x2; };

constexpr double cfloor(double v) { return (double)(long long)v; }  // v >= 0 only
constexpr double cround(double v) {  // np.round: half-to-even
    double f = cfloor(v);
    double fr = v - f;
    if (fr > 0.5) return f + 1.0;
    if (fr < 0.5) return f;
    return (((long long)f) & 1LL) ? f + 1.0 : f;
}

struct BoxArr { Box b[NR]; };

constexpr BoxArr make_boxes() {
    BoxArr out{};
    double rx_[14] = {}, ry_[14] = {}, wl_[14] = {};
    int nr = 0;
    for (int l = 1; l <= 3; ++l) {
        double wl  = cfloor(2.0 * 14.0 / (double)(l + 1));
        double wl2 = cfloor(wl / 2.0 - 1.0);
        double bb  = (l > 1) ? (14.0 - wl) / (double)(l - 1) : 0.0;
        double cen[3] = {};
        for (int k = 0; k < l; ++k) cen[k] = cfloor(wl2 + (double)k * bb) - wl2;
        for (int i = 0; i < l; ++i)
            for (int j = 0; j < l; ++j) { rx_[nr] = cen[j]; ry_[nr] = cen[i]; wl_[nr] = wl; ++nr; }
    }
    int nb = 0;
    for (int r = 0; r < nr; ++r) {
        for (int p = 1; p <= 2; ++p) {
            double len = wl_[r] / (double)p;
            for (int ix = 0; ix < p; ++ix)
                for (int jy = 0; jy < p; ++jy) {
                    int x1 = (int)cround(rx_[r] + ix * len);
                    int x2 = (int)cround(rx_[r] + ix * len + len);
                    int y1 = (int)cround(ry_[r] + jy * len);
                    int y2 = (int)cround(ry_[r] + jy * len + len);
                    out.b[nb] = Box{y1, y2, x1, x2};
                    ++nb;
                }
        }
    }
    return out;
}
constexpr BoxArr BOXES = make_boxes();

// distinct x-interval dedup
struct Meta { int nxi; int xlo[32]; int xhi[32]; int xid[NR]; };
constexpr Meta make_meta() {
    Meta m{};
    m.nxi = 0;
    for (int r = 0; r < NR; ++r) {
        int lo = BOXES.b[r].x1, hi = BOXES.b[r].x2, id = -1;
        for (int i = 0; i < m.nxi; ++i) if (m.xlo[i] == lo && m.xhi[i] == hi) { id = i; break; }
        if (id < 0) { id = m.nxi; m.xlo[id] = lo; m.xhi[id] = hi; m.nxi++; }
        m.xid[r] = id;
    }
    return m;
}
constexpr Meta MT = make_meta();
constexpr int NXI = MT.nxi;
static_assert(NXI == 14, "expected 14 distinct x-intervals");

__device__ __forceinline__ ushort f2bf(float f) {  // RNE float->bf16 (finite; -inf ok)
    union { float f; unsigned u; } v; v.f = f;
    unsigned r = v.u + 0x7FFFu + ((v.u >> 16) & 1u);
    return (ushort)(r >> 16);
}
__device__ __forceinline__ float bf2f(ushort u) {
    union { unsigned u; float f; } v; v.u = ((unsigned)u) << 16;
    return v.f;
}

// swizzled index into m_s[80][512]: 16B slots XOR'd by row&7 (matches GEMM read)
__device__ __forceinline__ int midx(int r, int c) {
    return r * Cc + (((c >> 3) ^ (r & 7)) << 3) + (c & 7);
}

// ---------------- kernel 0: W fp32 -> bf16 ----------------
__global__ __launch_bounds__(256) void k_convw(const float* __restrict__ w,
                                               ushort* __restrict__ o) {
    int i = (blockIdx.x * 256 + threadIdx.x) * 4;
    float4 f = *(const float4*)&w[i];
    ushort4 u;
    u.x = f2bf(f.x); u.y = f2bf(f.y); u.z = f2bf(f.z); u.w = f2bf(f.w);
    *(ushort4*)&o[i] = u;
}

// ---------------- fully fused: pool -> LDS m -> MFMA GEMM -> finish ----------------
// Round-0 structure + (1) per-block cg-stagger so concurrent blocks cover all four
// 512B quarters of each 2048B channel row (HBM channel balance), and (2) software-
// pipelined row prefetch: next pass's global loads issue before phase B (T14).
__global__ __launch_bounds__(512) void k_fused(const float* __restrict__ x,
                                               const ushort* __restrict__ wbf,
                                               const float* __restrict__ bias,
                                               float* __restrict__ out) {
    __shared__ __align__(16) ushort m_s[PadR * Cc];          // 80 KB, XOR-swizzled
    __shared__ __align__(16) union UU {
        ushort ims[Hh * NXI * 128];                          // 50 KB (pool passes)
        struct {                                             // epilogue scratch (aliased)
            float rowss[PadR][8];
            float rns[PadR];
            float y_s[Cc];
            float red2[8];
        } e;
    } u;
    __shared__ float ss_s[PadR];
    __shared__ float rnm[PadR];

    const int b = blockIdx.x;
    const int tid = threadIdx.x;
    const int lane = tid & 63;
    const int wv = tid >> 6;                // 0..7
    const int l15 = lane & 15, lhi = lane >> 4;

    // zero pad rows of m_s (rows 70..79) and tail of ss_s
    {
        uint* z = (uint*)&m_s[70 * Cc];
        #pragma unroll
        for (int i = 0; i < 5; ++i) z[tid + i * 512] = 0;    // 2560 uints
        if (tid >= 70 && tid < PadR) ss_s[tid] = 0.f;
    }

    float ssacc[9];
    #pragma unroll
    for (int i = 0; i < 9; ++i) ssacc[i] = 0.f;

    const int q  = tid & 31;                 // channel quad within 128
    const int hA = tid >> 5;                 // 0..15 (14..15 idle)
    const int c2 = tid & 63;                 // channel pair within 128
    const int grp = tid >> 6;                // wave = 9-box group
    const int st  = b & 3;                   // cg stagger phase

    // ---- pipelined row buffer (phase A loads), 14 float4 per thread ----
    float4 row[Ww];
    auto issueLoads = [&](int cg) {
        if (hA < Hh) {
            const float4* xq = (const float4*)(x + (size_t)b * Hh * Ww * Cc
                                               + (size_t)hA * Ww * Cc + cg * 128 + q * 4);
            #pragma unroll
            for (int w = 0; w < Ww; ++w) row[w] = xq[w * (Cc / 4)];
        }
    };
    auto foldRows = [&]() {                  // consume row[] -> ims (x-fold, bf16)
        if (hA < Hh) {
            #pragma unroll
            for (int xi = 0; xi < NXI; ++xi) {
                float4 mm = row[MT.xlo[xi]];
                #pragma unroll
                for (int w = MT.xlo[xi] + 1; w < MT.xhi[xi]; ++w) {
                    mm.x = fmaxf(mm.x, row[w].x); mm.y = fmaxf(mm.y, row[w].y);
                    mm.z = fmaxf(mm.z, row[w].z); mm.w = fmaxf(mm.w, row[w].w);
                }
                ushort4 o;
                o.x = f2bf(mm.x); o.y = f2bf(mm.y); o.z = f2bf(mm.z); o.w = f2bf(mm.w);
                *(ushort4*)&u.ims[(hA * NXI + xi) * 128 + q * 4] = o;
            }
        }
    };

    issueLoads(st);                          // prologue: first pass loads in flight

    for (int it = 0; it < 4; ++it) {
        const int cg = (it + st) & 3;        // staggered pass order
        // ---- phase A fold: consume in-flight loads -> ims ----
        foldRows();
        __syncthreads();                     // ims ready for phase B

        // ---- prefetch next pass rows (stream overlaps phase B) ----
        if (it < 3) issueLoads((it + 1 + st) & 3);

        // ---- phase B: y-fold (2 channels/thread), swizzled m_s write, reg SS ----
        auto fold = [&](auto GC) {
            constexpr int G = GC.value;
            #pragma unroll
            for (int i = 0; i < 9; ++i) {
                const int rr = G * 9 + i;                    // unroll-time constant
                if (rr < NR) {
                    float m0 = -INFINITY, m1 = -INFINITY;
                    #pragma unroll
                    for (int h = BOXES.b[rr < NR ? rr : 0].y1;
                         h < BOXES.b[rr < NR ? rr : 0].y2; ++h) {
                        ushort2 t2 = *(const ushort2*)
                            &u.ims[(h * NXI + MT.xid[rr < NR ? rr : 0]) * 128 + 2 * c2];
                        m0 = fmaxf(m0, bf2f(t2.x)); m1 = fmaxf(m1, bf2f(t2.y));
                    }
                    ushort2 o; o.x = f2bf(m0); o.y = f2bf(m1);
                    *(ushort2*)&m_s[midx(rr, cg * 128 + 2 * c2)] = o;
                    ssacc[i] += m0 * m0 + m1 * m1;
                }
            }
        };
        if      (grp == 0) fold(std::integral_constant<int, 0>{});
        else if (grp == 1) fold(std::integral_constant<int, 1>{});
        else if (grp == 2) fold(std::integral_constant<int, 2>{});
        else if (grp == 3) fold(std::integral_constant<int, 3>{});
        else if (grp == 4) fold(std::integral_constant<int, 4>{});
        else if (grp == 5) fold(std::integral_constant<int, 5>{});
        else if (grp == 6) fold(std::integral_constant<int, 6>{});
        else               fold(std::integral_constant<int, 7>{});
        __syncthreads();                      // ims consumed before next pass
    }

    // ---- publish SS (one butterfly per box), compute rnm ----
    #pragma unroll
    for (int i = 0; i < 9; ++i) {
        float s = ssacc[i];
        s += __shfl_xor(s, 1);  s += __shfl_xor(s, 2);  s += __shfl_xor(s, 4);
        s += __shfl_xor(s, 8);  s += __shfl_xor(s, 16); s += __shfl_xor(s, 32);
        if (lane == 0 && grp * 9 + i < NR) ss_s[grp * 9 + i] = s;
    }
    __syncthreads();
    if (tid < PadR) rnm[tid] = 1.f / fmaxf(sqrtf(ss_s[tid]), 1e-12f);
    __syncthreads();

    // ---- GEMM: t[80][512] = m * W^T, A resident in m_s, no barriers ----
    f32x4 acc[5][4];
    #pragma unroll
    for (int mi = 0; mi < 5; ++mi)
        #pragma unroll
        for (int ni = 0; ni < 4; ++ni) acc[mi][ni] = (f32x4){0.f, 0.f, 0.f, 0.f};

    auto loadB = [&](bf16x8 (&bf)[4][2], int k0) {
        #pragma unroll
        for (int ni = 0; ni < 4; ++ni)
            #pragma unroll
            for (int kh = 0; kh < 2; ++kh)
                bf[ni][kh] = *(const bf16x8*)(wbf + (size_t)(wv * 64 + ni * 16 + l15) * Cc
                                              + k0 + kh * 32 + lhi * 8);
    };

    bf16x8 bfc[4][2], bfn[4][2];
    loadB(bfc, 0);
    #pragma unroll
    for (int ks = 0; ks < 8; ++ks) {
        if (ks < 7) loadB(bfn, (ks + 1) * 64);
        #pragma unroll
        for (int kh = 0; kh < 2; ++kh) {
            bf16x8 af[5];
            #pragma unroll
            for (int mi = 0; mi < 5; ++mi) {
                int row_ = mi * 16 + l15;
                int slot = (ks * 8 + kh * 4 + lhi) ^ (row_ & 7);
                af[mi] = *(const bf16x8*)&m_s[row_ * Cc + slot * 8];
            }
            #pragma unroll
            for (int mi = 0; mi < 5; ++mi)
                #pragma unroll
                for (int ni = 0; ni < 4; ++ni)
                    acc[mi][ni] = __builtin_amdgcn_mfma_f32_16x16x32_bf16(
                        af[mi], bfc[ni][kh], acc[mi][ni], 0, 0, 0);
        }
        #pragma unroll
        for (int ni = 0; ni < 4; ++ni)
            #pragma unroll
            for (int kh = 0; kh < 2; ++kh) bfc[ni][kh] = bfn[ni][kh];
    }
    __syncthreads();                          // m_s/ims reads done; epilogue may alias

    // ---- fused epilogue: deferred A-norm + bias, row-norm, sum, final norm ----
    float bia[4];
    #pragma unroll
    for (int ni = 0; ni < 4; ++ni) bia[ni] = bias[wv * 64 + ni * 16 + l15];
    float rm[5][4];
    #pragma unroll
    for (int mi = 0; mi < 5; ++mi)
        #pragma unroll
        for (int j = 0; j < 4; ++j) rm[mi][j] = rnm[mi * 16 + lhi * 4 + j];
    #pragma unroll
    for (int mi = 0; mi < 5; ++mi)
        #pragma unroll
        for (int ni = 0; ni < 4; ++ni)
            #pragma unroll
            for (int j = 0; j < 4; ++j)
                acc[mi][ni][j] = fmaf(acc[mi][ni][j], rm[mi][j], bia[ni]);

    #pragma unroll
    for (int mi = 0; mi < 5; ++mi)
        #pragma unroll
        for (int j = 0; j < 4; ++j) {
            float s = 0.f;
            #pragma unroll
            for (int ni = 0; ni < 4; ++ni) s += acc[mi][ni][j] * acc[mi][ni][j];
            s += __shfl_xor(s, 1); s += __shfl_xor(s, 2);
            s += __shfl_xor(s, 4); s += __shfl_xor(s, 8);
            if (l15 == 0) u.e.rowss[mi * 16 + lhi * 4 + j][wv] = s;
        }
    __syncthreads();
    if (tid < PadR) {
        float s = 0.f;
        #pragma unroll
        for (int w8 = 0; w8 < 8; ++w8) s += u.e.rowss[tid][w8];
        u.e.rns[tid] = 1.f / fmaxf(sqrtf(s), 1e-12f);
    }
    __syncthreads();

    float ys[4] = {0.f, 0.f, 0.f, 0.f};
    #pragma unroll
    for (int mi = 0; mi < 5; ++mi)
        #pragma unroll
        for (int j = 0; j < 4; ++j) {
            int row_ = mi * 16 + lhi * 4 + j;
            float w = (row_ < NR) ? u.e.rns[row_] : 0.f;   // skip pad rows
            #pragma unroll
            for (int ni = 0; ni < 4; ++ni) ys[ni] = fmaf(acc[mi][ni][j], w, ys[ni]);
        }
    #pragma unroll
    for (int ni = 0; ni < 4; ++ni) {
        ys[ni] += __shfl_xor(ys[ni], 16);
        ys[ni] += __shfl_xor(ys[ni], 32);
    }
    if (lane < 16)
        #pragma unroll
        for (int ni = 0; ni < 4; ++ni) u.e.y_s[wv * 64 + ni * 16 + lane] = ys[ni];
    __syncthreads();

    float yv = u.e.y_s[tid];
    float s2 = yv * yv;
    s2 += __shfl_xor(s2, 1);  s2 += __shfl_xor(s2, 2);  s2 += __shfl_xor(s2, 4);
    s2 += __shfl_xor(s2, 8);  s2 += __shfl_xor(s2, 16); s2 += __shfl_xor(s2, 32);
    if (lane == 0) u.e.red2[wv] = s2;
    __syncthreads();
    float tot = 0.f;
    #pragma unroll
    for (int w8 = 0; w8 < 8; ++w8) tot += u.e.red2[w8];
    out[(size_t)b * Cc + tid] = yv / fmaxf(sqrtf(tot), 1e-12f);
}

// ---------------- launch ----------------
extern "C" void kernel_launch(void* const* d_in, const int* in_sizes, int n_in,
                              void* d_out, int out_size, void* d_ws, size_t ws_size,
                              hipStream_t stream) {
    const float* x  = (const float*)d_in[0];
    const float* pw = (const float*)d_in[1];
    const float* pb = (const float*)d_in[2];
    float* out = (float*)d_out;

    ushort* wbf = (ushort*)d_ws;                          // 512x512 bf16 = 0.5 MB

    k_convw<<<dim3(256), dim3(256), 0, stream>>>(pw, wbf);
    k_fused<<<dim3(Bb), dim3(512), 0, stream>>>(x, wbf, pb, out);
}